// Round 1
// baseline (790.151 us; speedup 1.0000x reference)
//
#include <hip/hip_runtime.h>

#define NB   4
#define CH   256
#define CQK  32
#define NPOS 4096
#define TJ   32
#define NCHUNK (NPOS / TJ)

// ---------------------------------------------------------------------------
// Fused QKV projection.  grid = NB * 20 * 4 = 320 blocks, 256 threads.
// Each block: one 16-row weight chunk (of the 320 total output rows
// [32 q | 32 k | 256 v]) x one 1024-position tile of one batch.
// W chunk lives in LDS (16KB); x streamed from global (L2-resident, the
// same x tile is consumed by 20 co-resident o-chunk blocks).
// ---------------------------------------------------------------------------
__global__ __launch_bounds__(256) void qkv_proj_kernel(
    const float* __restrict__ x,
    const float* __restrict__ wq, const float* __restrict__ bq,
    const float* __restrict__ wk, const float* __restrict__ bk,
    const float* __restrict__ wv, const float* __restrict__ bv,
    float* __restrict__ qo, float* __restrict__ ko, float* __restrict__ vo)
{
    __shared__ float wls[16][256];   // 16KB

    const int t  = threadIdx.x;
    const int bx = blockIdx.x;
    const int nt = bx & 3;           // 4 position tiles of 1024
    const int oc = (bx >> 2) % 20;   // 20 chunks of 16 output rows
    const int b  = bx / 80;

    const float* W; const float* bias; float* dst; int orow;
    if (oc < 2)      { W = wq + (size_t)oc * 16 * CH;       bias = bq + oc * 16;       dst = qo + (size_t)b * CQK * NPOS; orow = oc * 16; }
    else if (oc < 4) { W = wk + (size_t)(oc - 2) * 16 * CH; bias = bk + (oc - 2) * 16; dst = ko + (size_t)b * CQK * NPOS; orow = (oc - 2) * 16; }
    else             { W = wv + (size_t)(oc - 4) * 16 * CH; bias = bv + (oc - 4) * 16; dst = vo + (size_t)b * CH * NPOS;  orow = (oc - 4) * 16; }

    // load weight chunk (coalesced)
    #pragma unroll
    for (int i = 0; i < 16; ++i)
        wls[i][t] = W[i * 256 + t];
    __syncthreads();

    const float* xb = x + (size_t)b * CH * NPOS;
    const int nb = nt * 1024 + t;    // + j*256, j=0..3

    float acc[16][4];
    #pragma unroll
    for (int o = 0; o < 16; ++o)
        #pragma unroll
        for (int j = 0; j < 4; ++j) acc[o][j] = 0.f;

    for (int c = 0; c < 256; c += 4) {
        float xr[4][4];
        #pragma unroll
        for (int cc = 0; cc < 4; ++cc)
            #pragma unroll
            for (int j = 0; j < 4; ++j)
                xr[cc][j] = xb[(size_t)(c + cc) * NPOS + nb + j * 256];
        #pragma unroll
        for (int o = 0; o < 16; ++o) {
            float4 w4 = *(const float4*)&wls[o][c];   // wave-uniform -> LDS broadcast
            #pragma unroll
            for (int j = 0; j < 4; ++j)
                acc[o][j] += w4.x * xr[0][j] + w4.y * xr[1][j]
                           + w4.z * xr[2][j] + w4.w * xr[3][j];
        }
    }

    #pragma unroll
    for (int o = 0; o < 16; ++o) {
        float bb = bias[o];
        #pragma unroll
        for (int j = 0; j < 4; ++j)
            dst[(size_t)(orow + o) * NPOS + nb + j * 256] = acc[o][j] + bb;
    }
}

// ---------------------------------------------------------------------------
// Flash attention, fp32 vector.  grid = NB * (NPOS/64) = 256 blocks (1/CU),
// 256 threads (4 waves).  Per block: 64 query rows; loop over 128 j-chunks
// of 32 keys.  Online softmax (running m,l per row).  Next chunk's K/V
// global loads are issued into registers before PV so latency hides under
// compute (T14 async-STAGE).  Epilogue fuses gamma*res + input with an LDS
// transpose for coalesced output stores.
// Thread map: rgi = t>>4 (rows 4*rgi..+3), ci = t&15
//   S:  cols 2*ci, 2*ci+1
//   PV: channels 4*ci + 64*kk (+0..3), kk=0..3   (2-way LDS banks: free)
// ---------------------------------------------------------------------------
__global__ __launch_bounds__(256) void attn_kernel(
    const float* __restrict__ q,     // [B][32][N]
    const float* __restrict__ k,     // [B][32][N]
    const float* __restrict__ v,     // [B][256][N]
    const float* __restrict__ input, // [B][256][N]
    const float* __restrict__ gamma,
    float* __restrict__ out)
{
    __shared__ float qs[32][64];    //  8.0 KB
    __shared__ float ks[32][TJ];    //  4.0 KB
    __shared__ float vs[TJ][260];   // 33.3 KB
    __shared__ float ps[64][33];    //  8.4 KB   -> 53.7 KB total

    const int t  = threadIdx.x;
    const int b  = blockIdx.x >> 6;
    const int i0 = (blockIdx.x & 63) << 6;

    const float* qb = q + (size_t)b * CQK * NPOS;
    const float* kb = k + (size_t)b * CQK * NPOS;
    const float* vb = v + (size_t)b * CH * NPOS;

    // load Q tile: 32 x 64
    #pragma unroll
    for (int i = 0; i < 8; ++i) {
        int flat = i * 256 + t;
        qs[flat >> 6][flat & 63] = qb[(size_t)(flat >> 6) * NPOS + i0 + (flat & 63)];
    }

    const int rgi = t >> 4;   // 0..15
    const int ci  = t & 15;   // 0..15

    float m[4], l[4];
    float4 acc[4][4];
    #pragma unroll
    for (int r = 0; r < 4; ++r) {
        m[r] = -__builtin_inff(); l[r] = 0.f;
        #pragma unroll
        for (int kk = 0; kk < 4; ++kk) acc[r][kk] = make_float4(0.f, 0.f, 0.f, 0.f);
    }

    // prefetch registers: v tile 256x32 -> 8 float4/thread; k tile 32x32 -> 1 float4
    float4 vr[8]; float4 kr;
    auto issue_loads = [&](int j0) {
        #pragma unroll
        for (int i = 0; i < 8; ++i) {
            int flat = i * 256 + t;
            int c = flat >> 3, j4 = (flat & 7) * 4;
            vr[i] = *(const float4*)&vb[(size_t)c * NPOS + j0 + j4];
        }
        int d = t >> 3, j4 = (t & 7) * 4;
        kr = *(const float4*)&kb[(size_t)d * NPOS + j0 + j4];
    };
    issue_loads(0);

    for (int jc = 0; jc < NCHUNK; ++jc) {
        __syncthreads();                       // prev PV done reading vs/ks
        // stage prefetched tiles into LDS (v transposed: vs[j][c])
        #pragma unroll
        for (int i = 0; i < 8; ++i) {
            int flat = i * 256 + t;
            int c = flat >> 3, j4 = (flat & 7) * 4;
            vs[j4 + 0][c] = vr[i].x; vs[j4 + 1][c] = vr[i].y;
            vs[j4 + 2][c] = vr[i].z; vs[j4 + 3][c] = vr[i].w;
        }
        {
            int d = t >> 3, j4 = (t & 7) * 4;
            ks[d][j4 + 0] = kr.x; ks[d][j4 + 1] = kr.y;
            ks[d][j4 + 2] = kr.z; ks[d][j4 + 3] = kr.w;
        }
        if (jc + 1 < NCHUNK) issue_loads((jc + 1) * TJ);   // in flight across PV
        __syncthreads();

        // S = Q^T K  (rows 4rgi+r, cols 2ci+cc), contraction over d=32
        float s[4][2] = {{0.f,0.f},{0.f,0.f},{0.f,0.f},{0.f,0.f}};
        #pragma unroll 8
        for (int d = 0; d < 32; ++d) {
            float4 q4 = *(const float4*)&qs[d][rgi * 4];
            float2 k2 = *(const float2*)&ks[d][ci * 2];
            s[0][0] += q4.x * k2.x; s[0][1] += q4.x * k2.y;
            s[1][0] += q4.y * k2.x; s[1][1] += q4.y * k2.y;
            s[2][0] += q4.z * k2.x; s[2][1] += q4.z * k2.y;
            s[3][0] += q4.w * k2.x; s[3][1] += q4.w * k2.y;
        }

        // online softmax; reduce over the 16 ci lanes (lane bits 0..3)
        #pragma unroll
        for (int r = 0; r < 4; ++r) {
            float mx = fmaxf(s[r][0], s[r][1]);
            #pragma unroll
            for (int off = 1; off < 16; off <<= 1)
                mx = fmaxf(mx, __shfl_xor(mx, off, 64));
            float mn = fmaxf(m[r], mx);
            float sc = __expf(m[r] - mn);
            float p0 = __expf(s[r][0] - mn);
            float p1 = __expf(s[r][1] - mn);
            float ls = p0 + p1;
            #pragma unroll
            for (int off = 1; off < 16; off <<= 1)
                ls += __shfl_xor(ls, off, 64);
            l[r] = l[r] * sc + ls;
            m[r] = mn;
            #pragma unroll
            for (int kk = 0; kk < 4; ++kk) {
                acc[r][kk].x *= sc; acc[r][kk].y *= sc;
                acc[r][kk].z *= sc; acc[r][kk].w *= sc;
            }
            ps[rgi * 4 + r][ci * 2 + 0] = p0;
            ps[rgi * 4 + r][ci * 2 + 1] = p1;
        }
        __syncthreads();

        // PV: acc[r][kk] += p[r] * v[jj][4ci + 64kk ..+3]
        #pragma unroll 4
        for (int jj = 0; jj < TJ; ++jj) {
            float pr[4];
            #pragma unroll
            for (int r = 0; r < 4; ++r) pr[r] = ps[rgi * 4 + r][jj];
            float4 v4[4];
            #pragma unroll
            for (int kk = 0; kk < 4; ++kk)
                v4[kk] = *(const float4*)&vs[jj][ci * 4 + kk * 64];
            #pragma unroll
            for (int r = 0; r < 4; ++r)
                #pragma unroll
                for (int kk = 0; kk < 4; ++kk) {
                    acc[r][kk].x += pr[r] * v4[kk].x;
                    acc[r][kk].y += pr[r] * v4[kk].y;
                    acc[r][kk].z += pr[r] * v4[kk].z;
                    acc[r][kk].w += pr[r] * v4[kk].w;
                }
        }
    }

    // epilogue: out = gamma * (acc / l) + input, via LDS transpose (2 halves)
    float rl[4];
    #pragma unroll
    for (int r = 0; r < 4; ++r) rl[r] = 1.f / l[r];
    const float g = gamma[0];
    const float* inb = input + (size_t)b * CH * NPOS;
    float* ob = out + (size_t)b * CH * NPOS;

    for (int half = 0; half < 2; ++half) {
        __syncthreads();
        if ((rgi >> 3) == half) {
            int rb = (rgi & 7) * 4;
            #pragma unroll
            for (int r = 0; r < 4; ++r) {
                #pragma unroll
                for (int kk = 0; kk < 4; ++kk) {
                    vs[rb + r][ci * 4 + kk * 64 + 0] = acc[r][kk].x * rl[r];
                    vs[rb + r][ci * 4 + kk * 64 + 1] = acc[r][kk].y * rl[r];
                    vs[rb + r][ci * 4 + kk * 64 + 2] = acc[r][kk].z * rl[r];
                    vs[rb + r][ci * 4 + kk * 64 + 3] = acc[r][kk].w * rl[r];
                }
            }
        }
        __syncthreads();
        for (int it = 0; it < 32; ++it) {
            int flat = it * 256 + t;
            int ii = flat & 31;
            int c  = flat >> 5;
            size_t gidx = (size_t)c * NPOS + i0 + half * 32 + ii;
            ob[gidx] = g * vs[ii][c] + inb[gidx];
        }
    }
}

// ---------------------------------------------------------------------------
extern "C" void kernel_launch(void* const* d_in, const int* in_sizes, int n_in,
                              void* d_out, int out_size, void* d_ws, size_t ws_size,
                              hipStream_t stream) {
    const float* input = (const float*)d_in[0];
    const float* wq    = (const float*)d_in[1];
    const float* bq    = (const float*)d_in[2];
    const float* wk    = (const float*)d_in[3];
    const float* bk    = (const float*)d_in[4];
    const float* wv    = (const float*)d_in[5];
    const float* bv    = (const float*)d_in[6];
    const float* gamma = (const float*)d_in[7];
    float* out = (float*)d_out;

    const size_t qk_elems = (size_t)NB * CQK * NPOS;   // 524288
    const size_t v_elems  = (size_t)NB * CH * NPOS;    // 4194304
    if (ws_size < (2 * qk_elems + v_elems) * sizeof(float)) return;  // ~21 MB

    float* qw = (float*)d_ws;
    float* kw = qw + qk_elems;
    float* vw = kw + qk_elems;

    qkv_proj_kernel<<<dim3(NB * 20 * 4), dim3(256), 0, stream>>>(
        input, wq, bq, wk, bk, wv, bv, qw, kw, vw);
    attn_kernel<<<dim3(NB * (NPOS / 64)), dim3(256), 0, stream>>>(
        qw, kw, vw, input, gamma, out);
}

// Round 2
// 195.972 us; speedup vs baseline: 4.0320x; 4.0320x over previous
//
#include <hip/hip_runtime.h>

#define NB   4
#define CH   256
#define CQK  32
#define NPOS 4096
#define KT   64
#define NCHK (NPOS / KT)
#define QT   64

typedef __attribute__((ext_vector_type(8))) short bf16x8;
typedef __attribute__((ext_vector_type(4))) float f32x4;
typedef unsigned short u16;
typedef unsigned int   u32;

static __device__ __forceinline__ u16 f2bf(float x) {
    union { float f; u32 u; } c; c.f = x;
    u32 u = c.u + 0x7FFFu + ((c.u >> 16) & 1u);
    return (u16)(u >> 16);
}
static __device__ __forceinline__ u32 pack2(float a, float b) {
    return (u32)f2bf(a) | ((u32)f2bf(b) << 16);
}

// ---------------------------------------------------------------------------
// Fused QKV projection (fp32 math, bf16 outputs in MFMA layouts).
// q,k: [B][N][32] (d contiguous).  v: [B][256][N] with 32-pos interleave
// [0,16,1,17,...] so PV's P(u32-pair) and V k-orders match.
// grid = NB*20*4 = 320 blocks, 256 threads.
// ---------------------------------------------------------------------------
__global__ __launch_bounds__(256) void qkv_proj_kernel(
    const float* __restrict__ x,
    const float* __restrict__ wq, const float* __restrict__ bq,
    const float* __restrict__ wk, const float* __restrict__ bk,
    const float* __restrict__ wv, const float* __restrict__ bv,
    u16* __restrict__ qo, u16* __restrict__ ko, u16* __restrict__ vo)
{
    __shared__ float wls[16][256];

    const int t  = threadIdx.x;
    const int bx = blockIdx.x;
    const int nt = bx & 3;
    const int oc = (bx >> 2) % 20;
    const int b  = bx / 80;

    const float* W; const float* bias; int orow; int kind; // 0=q,1=k,2=v
    if (oc < 2)      { W = wq + (size_t)oc * 16 * CH;       bias = bq + oc * 16;       orow = oc * 16;       kind = 0; }
    else if (oc < 4) { W = wk + (size_t)(oc - 2) * 16 * CH; bias = bk + (oc - 2) * 16; orow = (oc - 2) * 16; kind = 1; }
    else             { W = wv + (size_t)(oc - 4) * 16 * CH; bias = bv + (oc - 4) * 16; orow = (oc - 4) * 16; kind = 2; }

    #pragma unroll
    for (int i = 0; i < 16; ++i)
        wls[i][t] = W[i * 256 + t];
    __syncthreads();

    float bl[16];
    #pragma unroll
    for (int o = 0; o < 16; ++o) bl[o] = bias[o];

    const float* xb = x + (size_t)b * CH * NPOS;
    const int nb = nt * 1024 + t;

    float acc[16][4];
    #pragma unroll
    for (int o = 0; o < 16; ++o)
        #pragma unroll
        for (int j = 0; j < 4; ++j) acc[o][j] = 0.f;

    for (int c = 0; c < 256; c += 4) {
        float xr[4][4];
        #pragma unroll
        for (int cc = 0; cc < 4; ++cc)
            #pragma unroll
            for (int j = 0; j < 4; ++j)
                xr[cc][j] = xb[(size_t)(c + cc) * NPOS + nb + j * 256];
        #pragma unroll
        for (int o = 0; o < 16; ++o) {
            float4 w4 = *(const float4*)&wls[o][c];
            #pragma unroll
            for (int j = 0; j < 4; ++j)
                acc[o][j] += w4.x * xr[0][j] + w4.y * xr[1][j]
                           + w4.z * xr[2][j] + w4.w * xr[3][j];
        }
    }

    if (kind < 2) {
        u16* dst = (kind == 0 ? qo : ko) + (size_t)b * NPOS * CQK;
        #pragma unroll
        for (int j = 0; j < 4; ++j) {
            int n = nb + j * 256;
            u32 wd[8];
            #pragma unroll
            for (int o2 = 0; o2 < 8; ++o2)
                wd[o2] = pack2(acc[2*o2][j] + bl[2*o2], acc[2*o2+1][j] + bl[2*o2+1]);
            uint4 A = make_uint4(wd[0], wd[1], wd[2], wd[3]);
            uint4 Bv = make_uint4(wd[4], wd[5], wd[6], wd[7]);
            *(uint4*)(dst + (size_t)n * CQK + orow)     = A;
            *(uint4*)(dst + (size_t)n * CQK + orow + 8) = Bv;
        }
    } else {
        u16* vdst = vo + (size_t)b * CH * NPOS;
        #pragma unroll
        for (int j = 0; j < 4; ++j) {
            int n = nb + j * 256;
            int islot = (n & ~31) + 2 * (n & 15) + ((n >> 4) & 1);
            #pragma unroll
            for (int o = 0; o < 16; ++o)
                vdst[(size_t)(orow + o) * NPOS + islot] = f2bf(acc[o][j] + bl[o]);
        }
    }
}

// ---------------------------------------------------------------------------
// bf16 MFMA flash attention.  grid 256 (1/CU), 256 threads = 4 waves.
// Block: 64 q rows of one batch. Wave w: QK^T strip rows [16w,16w+16) over
// KT=64 keys (mfma 16x16x32, K frags direct from L2), online softmax with
// defer-rescale, P -> swizzled dbuf LDS (1 raw barrier/chunk), PV: wave owns
// all 64 rows x 64 channels; V B-frags register-prefetched 1 chunk ahead
// from L2 (no V LDS). Epilogue: LDS transpose, coalesced fused residual.
// bid swizzle: xcd = bid%8 = batch*2+(tile&1) -> each XCD L2 serves 1 batch.
// ---------------------------------------------------------------------------
#define P_OFF   0        // 2 bufs x 4 strips x 16 rows x 128B = 16384
#define EP_STR  8704     // per-wave epilogue 32x68 f32
#define SC_OFF  34816    // 2 x 256B
#define FL_OFF  35328    // 2 x 16B
#define LL_OFF  35360    // 64 f32
#define SMEMSZ  35616

__global__ __launch_bounds__(256, 1) void attn_kernel(
    const u16* __restrict__ q, const u16* __restrict__ k, const u16* __restrict__ v,
    const float* __restrict__ input, const float* __restrict__ gamma,
    float* __restrict__ out)
{
    __shared__ __align__(16) char smem[SMEMSZ];

    const int t    = threadIdx.x;
    const int w    = t >> 6;
    const int lane = t & 63;
    const int g8   = lane >> 4;
    const int l16  = lane & 15;

    const int bid  = blockIdx.x;
    const int b    = (bid >> 1) & 3;
    const int tile = ((bid >> 3) << 1) | (bid & 1);
    const int i0   = tile * QT;

    const u16* qb = q + (size_t)b * NPOS * CQK;
    const u16* kb = k + (size_t)b * NPOS * CQK;
    const u16* vb = v + (size_t)b * CH * NPOS;

    // Q A-fragment (loop-invariant): rows i0+16w+l16, d = g8*8..+7
    bf16x8 qf = *(const bf16x8*)(qb + (size_t)(i0 + w * 16 + l16) * CQK + g8 * 8);

    bf16x8 kc[4], kn[4], vc[8], vn[8];
    #pragma unroll
    for (int nt = 0; nt < 4; ++nt)
        kc[nt] = *(const bf16x8*)(kb + (size_t)(nt * 16 + l16) * CQK + g8 * 8);
    #pragma unroll
    for (int nt = 0; nt < 4; ++nt)
        #pragma unroll
        for (int ks = 0; ks < 2; ++ks)
            vc[nt * 2 + ks] = *(const bf16x8*)(vb + (size_t)(w * 64 + nt * 16 + l16) * NPOS
                                               + ks * 32 + g8 * 8);

    f32x4 acc[4][4];
    #pragma unroll
    for (int mt = 0; mt < 4; ++mt)
        #pragma unroll
        for (int nt = 0; nt < 4; ++nt)
            acc[mt][nt] = (f32x4){0.f, 0.f, 0.f, 0.f};

    float m[4], l[4];
    #pragma unroll
    for (int r = 0; r < 4; ++r) { m[r] = -__builtin_inff(); l[r] = 0.f; }

    int buf = 0;
    for (int jc = 0; jc < NCHK; ++jc) {
        // ---- QK^T: S[16 x 64] for this wave's strip
        f32x4 z = {0.f, 0.f, 0.f, 0.f};
        f32x4 s[4];
        #pragma unroll
        for (int nt = 0; nt < 4; ++nt)
            s[nt] = __builtin_amdgcn_mfma_f32_16x16x32_bf16(qf, kc[nt], z, 0, 0, 0);

        // ---- prefetch next chunk's K/V B-frags (in flight across barrier+PV)
        if (jc + 1 < NCHK) {
            int j0n = (jc + 1) * KT;
            #pragma unroll
            for (int nt = 0; nt < 4; ++nt)
                kn[nt] = *(const bf16x8*)(kb + (size_t)(j0n + nt * 16 + l16) * CQK + g8 * 8);
            #pragma unroll
            for (int nt = 0; nt < 4; ++nt)
                #pragma unroll
                for (int ks = 0; ks < 2; ++ks)
                    vn[nt * 2 + ks] = *(const bf16x8*)(vb + (size_t)(w * 64 + nt * 16 + l16) * NPOS
                                                       + j0n + ks * 32 + g8 * 8);
        }

        // ---- online softmax (rows 4*g8+r of strip), defer-rescale THR=8
        char* pbase = smem + P_OFF + buf * 8192 + w * 2048;
        bool needany = false;
        float scr[4];
        #pragma unroll
        for (int r = 0; r < 4; ++r) {
            float mx = fmaxf(fmaxf(s[0][r], s[1][r]), fmaxf(s[2][r], s[3][r]));
            mx = fmaxf(mx, __shfl_xor(mx, 1));
            mx = fmaxf(mx, __shfl_xor(mx, 2));
            mx = fmaxf(mx, __shfl_xor(mx, 4));
            mx = fmaxf(mx, __shfl_xor(mx, 8));
            bool need = mx > m[r] + 8.0f;
            float sc = need ? __expf(m[r] - mx) : 1.0f;   // exp(-inf)=0 first time
            if (need) m[r] = mx;
            needany |= need;
            scr[r] = sc;
            float p0 = __expf(s[0][r] - m[r]);
            float p1 = __expf(s[1][r] - m[r]);
            float p2 = __expf(s[2][r] - m[r]);
            float p3 = __expf(s[3][r] - m[r]);
            int row = g8 * 4 + r;
            int swz = (row & 7) << 4;
            *(u32*)(pbase + row * 128 + ((l16 * 4) ^ swz))      = pack2(p0, p1);
            *(u32*)(pbase + row * 128 + ((64 + l16 * 4) ^ swz)) = pack2(p2, p3);
            float ls = (p0 + p1) + (p2 + p3);
            ls += __shfl_xor(ls, 1);
            ls += __shfl_xor(ls, 2);
            ls += __shfl_xor(ls, 4);
            ls += __shfl_xor(ls, 8);
            l[r] = l[r] * sc + ls;
        }
        if (l16 == 0) {
            f32x4 sc4 = {scr[0], scr[1], scr[2], scr[3]};
            *(f32x4*)(smem + SC_OFF + buf * 256 + (w * 16 + g8 * 4) * 4) = sc4;
        }
        bool wany = __any(needany);
        if (lane == 0)
            *(u32*)(smem + FL_OFF + buf * 16 + w * 4) = wany ? 1u : 0u;

        // ---- one barrier per chunk; keep global prefetch in flight
        asm volatile("s_waitcnt lgkmcnt(0)" ::: "memory");
        __builtin_amdgcn_s_barrier();
        asm volatile("" ::: "memory");
        __builtin_amdgcn_sched_barrier(0);

        // ---- conditional acc rescale
        uint4 fl = *(const uint4*)(smem + FL_OFF + buf * 16);
        if (fl.x | fl.y | fl.z | fl.w) {
            #pragma unroll
            for (int mt = 0; mt < 4; ++mt) {
                f32x4 ss = *(const f32x4*)(smem + SC_OFF + buf * 256 + (mt * 16 + g8 * 4) * 4);
                #pragma unroll
                for (int nt = 0; nt < 4; ++nt)
                    acc[mt][nt] *= ss;
            }
        }

        // ---- PV: acc[mt][nt] += P[strip mt] x V(regs)
        #pragma unroll
        for (int mt = 0; mt < 4; ++mt) {
            const char* pb = smem + P_OFF + buf * 8192 + mt * 2048 + l16 * 128;
            int swz = (l16 & 7) << 4;
            bf16x8 pa0 = *(const bf16x8*)(pb + ((g8 * 16) ^ swz));
            bf16x8 pa1 = *(const bf16x8*)(pb + ((64 + g8 * 16) ^ swz));
            #pragma unroll
            for (int nt = 0; nt < 4; ++nt) {
                acc[mt][nt] = __builtin_amdgcn_mfma_f32_16x16x32_bf16(pa0, vc[nt * 2 + 0], acc[mt][nt], 0, 0, 0);
                acc[mt][nt] = __builtin_amdgcn_mfma_f32_16x16x32_bf16(pa1, vc[nt * 2 + 1], acc[mt][nt], 0, 0, 0);
            }
        }

        if (jc + 1 < NCHK) {
            #pragma unroll
            for (int i = 0; i < 4; ++i) kc[i] = kn[i];
            #pragma unroll
            for (int i = 0; i < 8; ++i) vc[i] = vn[i];
        }
        buf ^= 1;
    }

    // ---- epilogue: out = gamma * (acc/l) + input, coalesced via LDS transpose
    if (l16 == 0) {
        f32x4 lv = {l[0], l[1], l[2], l[3]};
        *(f32x4*)(smem + LL_OFF + (w * 16 + g8 * 4) * 4) = lv;
    }
    __syncthreads();

    f32x4 linv[4];
    #pragma unroll
    for (int mt = 0; mt < 4; ++mt) {
        f32x4 lv = *(const f32x4*)(smem + LL_OFF + (mt * 16 + g8 * 4) * 4);
        f32x4 one = {1.f, 1.f, 1.f, 1.f};
        linv[mt] = one / lv;
    }

    const float gmm = gamma[0];
    const float* inb = input + (size_t)b * CH * NPOS;
    float* ob = out + (size_t)b * CH * NPOS;
    char* ep = smem + w * EP_STR;

    #pragma unroll
    for (int pass = 0; pass < 2; ++pass) {
        if (pass) asm volatile("s_waitcnt lgkmcnt(0)" ::: "memory");
        #pragma unroll
        for (int ntl = 0; ntl < 2; ++ntl) {
            int nt = pass * 2 + ntl;
            int cl = ntl * 16 + l16;
            #pragma unroll
            for (int mt = 0; mt < 4; ++mt) {
                f32x4 val = acc[mt][nt] * linv[mt];
                *(f32x4*)(ep + (cl * 68 + mt * 16 + g8 * 4) * 4) = val;
            }
        }
        asm volatile("s_waitcnt lgkmcnt(0)" ::: "memory");
        #pragma unroll
        for (int it = 0; it < 8; ++it) {
            int cl = it * 4 + g8;
            f32x4 o4 = *(const f32x4*)(ep + (cl * 68 + l16 * 4) * 4);
            int ch = w * 64 + pass * 32 + cl;
            size_t gi = (size_t)ch * NPOS + i0 + l16 * 4;
            float4 in4 = *(const float4*)(inb + gi);
            float4 r4;
            r4.x = gmm * o4[0] + in4.x;
            r4.y = gmm * o4[1] + in4.y;
            r4.z = gmm * o4[2] + in4.z;
            r4.w = gmm * o4[3] + in4.w;
            *(float4*)(ob + gi) = r4;
        }
    }
}

// ---------------------------------------------------------------------------
extern "C" void kernel_launch(void* const* d_in, const int* in_sizes, int n_in,
                              void* d_out, int out_size, void* d_ws, size_t ws_size,
                              hipStream_t stream) {
    const float* input = (const float*)d_in[0];
    const float* wq    = (const float*)d_in[1];
    const float* bq    = (const float*)d_in[2];
    const float* wk    = (const float*)d_in[3];
    const float* bk    = (const float*)d_in[4];
    const float* wv    = (const float*)d_in[5];
    const float* bv    = (const float*)d_in[6];
    const float* gamma = (const float*)d_in[7];
    float* out = (float*)d_out;

    const size_t qk_elems = (size_t)NB * NPOS * CQK;   // 524288
    const size_t v_elems  = (size_t)NB * CH * NPOS;    // 4194304
    if (ws_size < (2 * qk_elems + v_elems) * sizeof(u16)) return;  // ~10.5 MB

    u16* qw = (u16*)d_ws;
    u16* kw = qw + qk_elems;
    u16* vw = kw + qk_elems;

    qkv_proj_kernel<<<dim3(NB * 20 * 4), dim3(256), 0, stream>>>(
        input, wq, bq, wk, bk, wv, bv, qw, kw, vw);
    attn_kernel<<<dim3(NB * (NPOS / QT)), dim3(256), 0, stream>>>(
        qw, kw, vw, input, gamma, out);
}